// Round 11
// baseline (1005.795 us; speedup 1.0000x reference)
//
#include <hip/hip_runtime.h>
#include <hip/hip_bf16.h>
#include <stdint.h>

#define H 256
#define W 512
#define NCG 18                      // 144/8 channel groups
#define AW 520                      // padded cols: x in [-2, 517]
#define AH 258                      // padded rows: y in [-2, 255]
// fp8 activation planes
#define XB8 8                       // 8 fp8 per pixel per ci-group
#define ROWF8 (AW*XB8)              // 4160 B
#define CGF8 ((size_t)AH*ROWF8)     // 1,073,280 B per plane
#define ACTF8 ((size_t)NCG*CGF8)    // 19.3 MB per fp8 buffer
// fp8 packed weights: K = 13*18=234 kgroups of 8, pad to 240 = 15 chunks of 128
#define NCH8 15
#define CHB8 18432                  // 9 m-tiles * 2048 B per K128 chunk
#define CHBF8 8192                  // 4 m-tiles * 2048 B (final layer)
#define WPH8 ((size_t)NCH8*CHB8)    // 276,480 B per hidden layer
#define WPF8 ((size_t)NCH8*CHBF8)   // 122,880 B final layer

typedef float f32x4 __attribute__((ext_vector_type(4)));
typedef int   i32x4 __attribute__((ext_vector_type(4)));
typedef int   i32x8 __attribute__((ext_vector_type(8)));

__device__ __forceinline__ unsigned char f2e4(float f) {
  int v = __builtin_amdgcn_cvt_pk_fp8_f32(f, 0.f, 0, false);
  return (unsigned char)(v & 0xff);
}
__device__ __forceinline__ unsigned int pk4e4(float v0, float v1, float v2, float v3) {
  int p = __builtin_amdgcn_cvt_pk_fp8_f32(v0, v1, 0, false);
  p = __builtin_amdgcn_cvt_pk_fp8_f32(v2, v3, p, true);
  return (unsigned int)p;
}
__device__ __forceinline__ void gload_lds16(const void* g, void* l) {
  __builtin_amdgcn_global_load_lds(
      (const __attribute__((address_space(1))) unsigned int*)g,
      (__attribute__((address_space(3))) unsigned int*)l, 16, 0, 0);
}
// MX-scaled fp8 MFMA, both operands e4m3, all scale bytes = 0x7F (1.0).
__device__ __forceinline__ f32x4 mfma8(i32x8 a, i32x8 b, f32x4 c) {
  return __builtin_amdgcn_mfma_scale_f32_16x16x128_f8f6f4(
      a, b, c, 0, 0, 0, 0x7F7F7F7F, 0, 0x7F7F7F7F);
}

// ---------------- weight packing (fp8) ----------------
// K order ci-group-major: kgrp = (ci/8)*13 + tap. Fragment: lane l holds
// co = l&15, k-block = l>>4 (32 k each); byte e of the 32B fragment is
// k = (l>>4)*32 + e, stored as [chunk][m][half e>>4][lane][16B].
__global__ void k_pack_h8(const float* __restrict__ wr, char* __restrict__ wph) {
  int idx = blockIdx.x * 256 + threadIdx.x;
  if (idx >= 10 * 144 * 144) return;
  int ci = idx % 144; int rem = idx / 144; int co = rem % 144; int layer = rem / 144;
  const float* src = wr + (size_t)((layer * 144 + co) * 144 + ci) * 25;
  char* dstL = wph + (size_t)layer * WPH8;
  int m = co >> 4, l_lo = co & 15;
#pragma unroll
  for (int tap = 0; tap < 13; ++tap) {
    int ky = (tap >= 5) + (tap >= 10);
    int kx = tap - ky * 5;
    int k = ((ci >> 3) * 13 + tap) * 8 + (ci & 7);
    int chunk = k >> 7, kr = k & 127, g = kr >> 5, e = kr & 31;
    dstL[(size_t)(chunk * 9 + m) * 2048 + (e >> 4) * 1024 + (g * 16 + l_lo) * 16 + (e & 15)]
        = (char)f2e4(src[ky * 5 + kx]);
  }
}
__global__ void k_pack_f8(const float* __restrict__ wf, char* __restrict__ wpf) {
  int idx = blockIdx.x * 256 + threadIdx.x;
  if (idx >= 49 * 144) return;
  int ci = idx % 144; int co = idx / 144;
  const float* src = wf + (size_t)(co * 144 + ci) * 25;
  int m = co >> 4, l_lo = co & 15;
#pragma unroll
  for (int tap = 0; tap < 13; ++tap) {
    int ky = (tap >= 5) + (tap >= 10);
    int kx = tap - ky * 5;
    int k = ((ci >> 3) * 13 + tap) * 8 + (ci & 7);
    int chunk = k >> 7, kr = k & 127, g = kr >> 5, e = kr & 31;
    wpf[(size_t)(chunk * 4 + m) * 2048 + (e >> 4) * 1024 + (g * 16 + l_lo) * 16 + (e & 15)]
        = (char)f2e4(src[ky * 5 + kx]);
  }
}
__global__ void k_biaspad(const float* __restrict__ bf, float* __restrict__ bfp) {
  int i = threadIdx.x;
  bfp[i] = (i < 49) ? bf[i] : -1e30f;
}

// zero fp8 activation pads: rows 0-1 full + cols {0,1,514,515} rows 2..257,
// for both fp8 buffers, all 18 planes (8B slots).
__global__ void k_zeropad8(char* __restrict__ a8, char* __restrict__ b8) {
  int i = blockIdx.x * 256 + threadIdx.x;
  if (i >= 2 * 18 * 2064) return;
  int s = i % 2064; int p = i / 2064; int cig = p % 18; int buf = p / 18;
  char* base = (buf ? b8 : a8) + (size_t)cig * CGF8;
  int row, colpx;
  if (s < 1040) { row = s / 520; colpx = s - row * 520; }
  else { int s2 = s - 1040; row = 2 + (s2 >> 2); int m = s2 & 3; colpx = (m < 2) ? m : (512 + m); }
  uint2 z; z.x = 0u; z.y = 0u;
  *(uint2*)(base + (size_t)row * ROWF8 + (size_t)colpx * 8) = z;
}

// ---------------- first layer: 1 -> 144, strictly causal (12 taps) ----------------
__global__ void k_layer0(const float* __restrict__ x, const float* __restrict__ w0,
                         const float* __restrict__ b0, char* __restrict__ act8) {
  int i = blockIdx.x * 256 + threadIdx.x;   // one thread per pixel
  int y = i >> 9, xx = i & 511;
  float xv[12];
#pragma unroll
  for (int tp = 0; tp < 12; ++tp) {
    int ky = (tp >= 5) + (tp >= 10);
    int kx = tp - ky * 5;
    int yy = y + ky - 2, xs = xx + kx - 2;
    bool ok = (yy >= 0) && (xs >= 0) && (xs < W);
    xv[tp] = ok ? x[yy * W + xs] : 0.f;
  }
  char* ob8 = act8 + (size_t)(y + 2) * ROWF8 + (size_t)(xx + 2) * 8;
  for (int cg = 0; cg < NCG; ++cg) {
    float av[8];
#pragma unroll
    for (int p = 0; p < 8; ++p) {
      int co = cg * 8 + p;
      float a = b0[co];
#pragma unroll
      for (int tp = 0; tp < 12; ++tp) {
        int ky = (tp >= 5) + (tp >= 10);
        int kx = tp - ky * 5;
        a += w0[co * 25 + ky * 5 + kx] * xv[tp];
      }
      av[p] = fmaxf(a, 0.f);
    }
    uint2 v8;
    v8.x = pk4e4(av[0], av[1], av[2], av[3]);
    v8.y = pk4e4(av[4], av[5], av[6], av[7]);
    *(uint2*)(ob8 + (size_t)cg * CGF8) = v8;
  }
}

// ---------------- hidden conv: 144 -> 144, 13 taps, MX-fp8 MFMA K=128 ----------------
// Residual lives in fp8: res=1 reads out8's own-pixel slot (h), adds after
// relu, and writes back in place (input halo comes from the OTHER buffer, so
// no race). Epilogue merges lane pairs via shfl_xor(16) so stores are
// contiguous 8B uint2 per active lane (2x128B per instruction) -- kills the
// 4B-interleaved-store write amplification seen in round 9.
__global__ __launch_bounds__(256, 3)
void k_conv(const char* __restrict__ in, char* __restrict__ out8,
            const char* __restrict__ wp, const float* __restrict__ bias, int res) {
  __shared__ __align__(16) char lA[2][CHB8];
  const int tid = threadIdx.x;
  const int wid = tid >> 6, lane = tid & 63;
  const int col = lane & 15, g = lane >> 4;

  int bid = blockIdx.x;                 // 1024 blocks
  int xcd = bid & 7, idx = bid >> 3;    // idx in [0,128)
  int by = xcd * 8 + (idx >> 4), bx = idx & 15;   // XCD: contiguous 32-row band
  int y = by * 4 + wid, x0 = bx * 32;

  int pxo[2];
#pragma unroll
  for (int t = 0; t < 2; ++t) pxo[t] = (x0 + 16 * t + col) * XB8;
  const char* bbase = in + (size_t)y * ROWF8;

  f32x4 acc[9][2];
#pragma unroll
  for (int m = 0; m < 9; ++m)
#pragma unroll
    for (int t = 0; t < 2; ++t) acc[m][t] = (f32x4){0.f, 0.f, 0.f, 0.f};

  i32x8 bA[2], bB[2];

  // per-lane K state: base kgroup of this lane's k-block = 16c + 4g,
  // tracked as (cig, tap); advances +16 kgroups per chunk.
  int tap = 4 * g, cig = 0;
  auto bload = [&](i32x8 (&dst)[2]) __attribute__((always_inline)) {
#pragma unroll
    for (int s = 0; s < 4; ++s) {
      int ts = tap + s, cs = cig;
      if (ts >= 13) { ts -= 13; cs += 1; }
      if (cs >= 18) { cs = 0; ts = 0; }   // pad kgroups: zero weights, any valid addr
      int ky = (ts >= 5) + (ts >= 10);
      int kx = ts - ky * 5;
      int off = cs * (int)CGF8 + ky * (int)ROWF8 + kx * 8;
#pragma unroll
      for (int t = 0; t < 2; ++t) {
        uint2 u = *(const uint2*)(bbase + (size_t)(off + pxo[t]));
        dst[t][2 * s] = (int)u.x; dst[t][2 * s + 1] = (int)u.y;
      }
    }
    tap += 3; ++cig; if (tap >= 13) { tap -= 13; ++cig; }
  };

  // 18 DMA instr per chunk split over 4 waves (5,5,4,4)
  auto stage = [&](char* ldsn, int c) __attribute__((always_inline)) {
    const char* wsrc = wp + (size_t)c * CHB8;
#pragma unroll
    for (int j0 = 0; j0 < 5; ++j0) {
      int j = wid + j0 * 4;
      if (j < 18) gload_lds16(wsrc + (size_t)j * 1024 + (lane << 4), ldsn + j * 1024);
    }
  };

  auto domfma = [&](const char* ldsc, i32x8 (&b)[2]) __attribute__((always_inline)) {
    __builtin_amdgcn_s_setprio(1);
#pragma unroll
    for (int m = 0; m < 9; ++m) {
      i32x4 lo = *(const i32x4*)(ldsc + m * 2048 + (lane << 4));
      i32x4 hi = *(const i32x4*)(ldsc + m * 2048 + 1024 + (lane << 4));
      i32x8 a = __builtin_shufflevector(lo, hi, 0, 1, 2, 3, 4, 5, 6, 7);
#pragma unroll
      for (int t = 0; t < 2; ++t) acc[m][t] = mfma8(a, b[t], acc[m][t]);
    }
    __builtin_amdgcn_s_setprio(0);
  };

  auto phase = [&](const char* ldsc, char* ldsn, i32x8 (&bcur)[2], i32x8 (&bnext)[2],
                   int c) __attribute__((always_inline)) {
    stage(ldsn, c + 1);
    asm volatile("" ::: "memory");      // stage issues precede B prefetch (vmcnt order)
    bload(bnext);                       // chunk c+1
    asm volatile("" ::: "memory");
    domfma(ldsc, bcur);
    asm volatile("s_waitcnt vmcnt(8)" ::: "memory");  // stage done; 8 B loads in flight
    __builtin_amdgcn_s_barrier();
    asm volatile("" ::: "memory");
  };

  // prologue: chunk 0
  stage(&lA[0][0], 0);
  asm volatile("" ::: "memory");
  bload(bA);                            // chunk 0
  asm volatile("s_waitcnt vmcnt(8)" ::: "memory");
  __builtin_amdgcn_s_barrier();
  asm volatile("" ::: "memory");

#pragma unroll 1
  for (int c = 0; c < NCH8 - 1; c += 2) {   // 7 pairs: chunks 0..13
    phase(&lA[0][0], &lA[1][0], bA, bB, c);
    phase(&lA[1][0], &lA[0][0], bB, bA, c + 1);
  }
  domfma(&lA[0][0], bA);                // chunk 14 (even -> buffer 0)

  // epilogue: +bias, relu, fp8 residual (in place), shfl-merged 8B stores.
  // C/D: col=lane&15(px), row=(lane>>4)*4+r -> co = m*16 + g*4 + r.
  // Even-g lane gathers partner's 4 ch -> full 8-ch plane slot -> uint2 store.
#pragma unroll
  for (int m = 0; m < 9; ++m) {
    int co0 = m * 16 + (g << 2);
    f32x4 bv = *(const f32x4*)(bias + co0);
    int plane = m * 2 + (g >> 1);
#pragma unroll
    for (int t = 0; t < 2; ++t) {
      int px = x0 + 16 * t + col;
      float v0 = fmaxf(acc[m][t][0] + bv[0], 0.f);
      float v1 = fmaxf(acc[m][t][1] + bv[1], 0.f);
      float v2 = fmaxf(acc[m][t][2] + bv[2], 0.f);
      float v3 = fmaxf(acc[m][t][3] + bv[3], 0.f);
      float w0 = __shfl_xor(v0, 16);    // partner quarter-wave (g^1)
      float w1 = __shfl_xor(v1, 16);
      float w2 = __shfl_xor(v2, 16);
      float w3 = __shfl_xor(v3, 16);
      if ((g & 1) == 0) {
        char* o8 = out8 + (size_t)plane * CGF8 + (size_t)(y + 2) * ROWF8
                 + (size_t)(px + 2) * 8;
        if (res) {
          uint2 hv = *(const uint2*)o8;
          v0 += __builtin_amdgcn_cvt_f32_fp8((int)hv.x, 0);
          v1 += __builtin_amdgcn_cvt_f32_fp8((int)hv.x, 1);
          v2 += __builtin_amdgcn_cvt_f32_fp8((int)hv.x, 2);
          v3 += __builtin_amdgcn_cvt_f32_fp8((int)hv.x, 3);
          w0 += __builtin_amdgcn_cvt_f32_fp8((int)hv.y, 0);
          w1 += __builtin_amdgcn_cvt_f32_fp8((int)hv.y, 1);
          w2 += __builtin_amdgcn_cvt_f32_fp8((int)hv.y, 2);
          w3 += __builtin_amdgcn_cvt_f32_fp8((int)hv.y, 3);
        }
        uint2 st;
        st.x = pk4e4(v0, v1, v2, v3);
        st.y = pk4e4(w0, w1, w2, w3);
        *(uint2*)o8 = st;
      }
    }
  }
}

// ---------------- final conv (144 -> 49 padded 64, fp8) + softmax ----------------
__global__ __launch_bounds__(256, 4)
void k_convf(const char* __restrict__ in, float* __restrict__ probs,
             const char* __restrict__ wp, const float* __restrict__ bfp) {
  __shared__ __align__(16) char lA[2][CHBF8];
  const int tid = threadIdx.x;
  const int wid = tid >> 6, lane = tid & 63;
  const int col = lane & 15, g = lane >> 4;

  int bid = blockIdx.x;
  int xcd = bid & 7, idx = bid >> 3;
  int by = xcd * 8 + (idx >> 4), bx = idx & 15;
  int y = by * 4 + wid, x0 = bx * 32;

  int pxo[2];
#pragma unroll
  for (int t = 0; t < 2; ++t) pxo[t] = (x0 + 16 * t + col) * XB8;
  const char* bbase = in + (size_t)y * ROWF8;

  f32x4 acc[4][2];
#pragma unroll
  for (int m = 0; m < 4; ++m)
#pragma unroll
    for (int t = 0; t < 2; ++t) acc[m][t] = (f32x4){0.f, 0.f, 0.f, 0.f};

  i32x8 bA[2], bB[2];

  int tap = 4 * g, cig = 0;
  auto bload = [&](i32x8 (&dst)[2]) __attribute__((always_inline)) {
#pragma unroll
    for (int s = 0; s < 4; ++s) {
      int ts = tap + s, cs = cig;
      if (ts >= 13) { ts -= 13; cs += 1; }
      if (cs >= 18) { cs = 0; ts = 0; }
      int ky = (ts >= 5) + (ts >= 10);
      int kx = ts - ky * 5;
      int off = cs * (int)CGF8 + ky * (int)ROWF8 + kx * 8;
#pragma unroll
      for (int t = 0; t < 2; ++t) {
        uint2 u = *(const uint2*)(bbase + (size_t)(off + pxo[t]));
        dst[t][2 * s] = (int)u.x; dst[t][2 * s + 1] = (int)u.y;
      }
    }
    tap += 3; ++cig; if (tap >= 13) { tap -= 13; ++cig; }
  };

  auto stage = [&](char* ldsn, int c) __attribute__((always_inline)) {
    const char* wsrc = wp + (size_t)c * CHBF8;
#pragma unroll
    for (int j0 = 0; j0 < 2; ++j0) {
      int j = wid + j0 * 4;
      gload_lds16(wsrc + (size_t)j * 1024 + (lane << 4), ldsn + j * 1024);
    }
  };

  auto domfma = [&](const char* ldsc, i32x8 (&b)[2]) __attribute__((always_inline)) {
    __builtin_amdgcn_s_setprio(1);
#pragma unroll
    for (int m = 0; m < 4; ++m) {
      i32x4 lo = *(const i32x4*)(ldsc + m * 2048 + (lane << 4));
      i32x4 hi = *(const i32x4*)(ldsc + m * 2048 + 1024 + (lane << 4));
      i32x8 a = __builtin_shufflevector(lo, hi, 0, 1, 2, 3, 4, 5, 6, 7);
#pragma unroll
      for (int t = 0; t < 2; ++t) acc[m][t] = mfma8(a, b[t], acc[m][t]);
    }
    __builtin_amdgcn_s_setprio(0);
  };

  auto phase = [&](const char* ldsc, char* ldsn, i32x8 (&bcur)[2], i32x8 (&bnext)[2],
                   int c) __attribute__((always_inline)) {
    stage(ldsn, c + 1);
    asm volatile("" ::: "memory");
    bload(bnext);
    asm volatile("" ::: "memory");
    domfma(ldsc, bcur);
    asm volatile("s_waitcnt vmcnt(8)" ::: "memory");
    __builtin_amdgcn_s_barrier();
    asm volatile("" ::: "memory");
  };

  stage(&lA[0][0], 0);
  asm volatile("" ::: "memory");
  bload(bA);
  asm volatile("s_waitcnt vmcnt(8)" ::: "memory");
  __builtin_amdgcn_s_barrier();
  asm volatile("" ::: "memory");

#pragma unroll 1
  for (int c = 0; c < NCH8 - 1; c += 2) {
    phase(&lA[0][0], &lA[1][0], bA, bB, c);
    phase(&lA[1][0], &lA[0][0], bB, bA, c + 1);
  }
  domfma(&lA[0][0], bA);

  // softmax over 49 channels per pixel; lanes (col, g0..3) hold the channel spread
#pragma unroll
  for (int t = 0; t < 2; ++t) {
    float lg[4][4];
    float mx = -1e30f;
#pragma unroll
    for (int m = 0; m < 4; ++m) {
      f32x4 bv = *(const f32x4*)(bfp + m * 16 + (g << 2));
#pragma unroll
      for (int r = 0; r < 4; ++r) {
        lg[m][r] = acc[m][t][r] + bv[r];
        mx = fmaxf(mx, lg[m][r]);
      }
    }
    mx = fmaxf(mx, __shfl_xor(mx, 16));
    mx = fmaxf(mx, __shfl_xor(mx, 32));
    float s = 0.f;
#pragma unroll
    for (int m = 0; m < 4; ++m)
#pragma unroll
      for (int r = 0; r < 4; ++r) {
        lg[m][r] = __expf(lg[m][r] - mx);
        s += lg[m][r];
      }
    s += __shfl_xor(s, 16);
    s += __shfl_xor(s, 32);
    float inv = 1.f / s;
    int xp = x0 + 16 * t + col;
    float* op = probs + (size_t)y * W + xp;
#pragma unroll
    for (int m = 0; m < 4; ++m)
#pragma unroll
      for (int r = 0; r < 4; ++r) {
        int co = m * 16 + (g << 2) + r;
        if (co < 49) op[(size_t)co * (H * W)] = lg[m][r] * inv;
      }
  }
}

// ---------------- importance mask + depth-to-space ----------------
__global__ void k_tmask(const float* __restrict__ x, float* __restrict__ out1) {
  int i = blockIdx.x * 256 + threadIdx.x;   // over 512*1024 outputs per g
  int yy = i >> 10, xx = i & 1023;
  float xv = x[(yy >> 1) * W + (xx >> 1)];
  float tc = floorf((xv + 1.0f) / (float)(2.0 / 47.0) + 1e-5f);
#pragma unroll 4
  for (int g = 0; g < 48; ++g)
    out1[(size_t)g * (512 * 1024) + i] = ((float)g < tc) ? 1.0f : 0.0f;
}

extern "C" void kernel_launch(void* const* d_in, const int* in_sizes, int n_in,
                              void* d_out, int out_size, void* d_ws, size_t ws_size,
                              hipStream_t stream) {
  const float* x  = (const float*)d_in[0];
  const float* w0 = (const float*)d_in[1];
  const float* b0 = (const float*)d_in[2];
  const float* wr = (const float*)d_in[3];
  const float* br = (const float*)d_in[4];
  const float* wf = (const float*)d_in[5];
  const float* bf = (const float*)d_in[6];

  char* ws    = (char*)d_ws;
  char* a8    = ws;                     // fp8 h stream (residual lives here)
  char* b8    = ws + ACTF8;             // fp8 y stream
  char* wph8  = ws + 2 * ACTF8;
  char* wpf8  = wph8 + 10 * WPH8;
  float* bfp  = (float*)(wpf8 + WPF8);

  // zero fp8 weight pad regions (kgroups 234-239, final co 49..63) + bfp tail
  hipMemsetAsync(wph8, 0, 10 * WPH8 + WPF8 + 256, stream);
  // zero fp8 activation pads
  k_zeropad8<<<(2 * 18 * 2064 + 255) / 256, 256, 0, stream>>>(a8, b8);

  k_pack_h8<<<(10 * 144 * 144 + 255) / 256, 256, 0, stream>>>(wr, wph8);
  k_pack_f8<<<(49 * 144 + 255) / 256, 256, 0, stream>>>(wf, wpf8);
  k_biaspad<<<1, 64, 0, stream>>>(bf, bfp);

  k_layer0<<<512, 256, 0, stream>>>(x, w0, b0, a8);

  for (int i = 0; i < 5; ++i) {
    // y = relu(conv(h)): a8 -> b8
    k_conv<<<1024, 256, 0, stream>>>(a8, b8, wph8 + (size_t)(2 * i) * WPH8,
                                     br + (2 * i) * 144, 0);
    // h = h + relu(conv(y)): b8 -> a8 (residual read-modify-write in place)
    k_conv<<<1024, 256, 0, stream>>>(b8, a8, wph8 + (size_t)(2 * i + 1) * WPH8,
                                     br + (2 * i + 1) * 144, 1);
  }

  float* probs = (float*)d_out;
  k_convf<<<1024, 256, 0, stream>>>(a8, probs, wpf8, bfp);
  k_tmask<<<2048, 256, 0, stream>>>(x, probs + (size_t)49 * H * W);
}

// Round 14
// 1003.084 us; speedup vs baseline: 1.0027x; 1.0027x over previous
//
#include <hip/hip_runtime.h>
#include <hip/hip_bf16.h>
#include <stdint.h>

#define H 256
#define W 512
#define NCG 18                      // 144/8 channel groups
#define AH 258                      // padded rows: y in [-2, 255]
// fp8 activation planes -- 128B-ALIGNED layout: 16-px left halo so every
// 16-lane 128B store chunk is exactly one L2 line (fixes 8.5x write amp).
#define AWF 544                     // 16 halo + 512 + 16 halo
#define XB8 8                       // 8 fp8 per pixel per ci-group
#define ROWF8 (AWF*XB8)             // 4352 B = 34*128
#define CGF8 ((size_t)AH*ROWF8)     // 1,122,816 B per plane (128-aligned)
#define ACTF8 ((size_t)NCG*CGF8)    // 20.2 MB per fp8 buffer
// fp8 packed weights: K = 13*18=234 kgroups of 8, pad to 240 = 15 chunks of 128
#define NCH8 15
#define CHB8 18432                  // 9 m-tiles * 2048 B per K128 chunk
#define CHBF8 8192                  // 4 m-tiles * 2048 B (final layer)
#define WPH8 ((size_t)NCH8*CHB8)    // 276,480 B per hidden layer
#define WPF8 ((size_t)NCH8*CHBF8)   // 122,880 B final layer

typedef float f32x4 __attribute__((ext_vector_type(4)));
typedef int   i32x4 __attribute__((ext_vector_type(4)));
typedef int   i32x8 __attribute__((ext_vector_type(8)));

__device__ __forceinline__ unsigned char f2e4(float f) {
  int v = __builtin_amdgcn_cvt_pk_fp8_f32(f, 0.f, 0, false);
  return (unsigned char)(v & 0xff);
}
__device__ __forceinline__ unsigned int pk4e4(float v0, float v1, float v2, float v3) {
  int p = __builtin_amdgcn_cvt_pk_fp8_f32(v0, v1, 0, false);
  p = __builtin_amdgcn_cvt_pk_fp8_f32(v2, v3, p, true);
  return (unsigned int)p;
}
__device__ __forceinline__ void gload_lds16(const void* g, void* l) {
  __builtin_amdgcn_global_load_lds(
      (const __attribute__((address_space(1))) unsigned int*)g,
      (__attribute__((address_space(3))) unsigned int*)l, 16, 0, 0);
}
// MX-scaled fp8 MFMA, both operands e4m3, all scale bytes = 0x7F (1.0).
__device__ __forceinline__ f32x4 mfma8(i32x8 a, i32x8 b, f32x4 c) {
  return __builtin_amdgcn_mfma_scale_f32_16x16x128_f8f6f4(
      a, b, c, 0, 0, 0, 0x7F7F7F7F, 0, 0x7F7F7F7F);
}

// ---------------- weight packing (fp8) ----------------
// K order ci-group-major: kgrp = (ci/8)*13 + tap. Fragment: lane l holds
// co = l&15, k-block = l>>4 (32 k each); byte e of the 32B fragment is
// k = (l>>4)*32 + e, stored as [chunk][m][half e>>4][lane][16B].
__global__ void k_pack_h8(const float* __restrict__ wr, char* __restrict__ wph) {
  int idx = blockIdx.x * 256 + threadIdx.x;
  if (idx >= 10 * 144 * 144) return;
  int ci = idx % 144; int rem = idx / 144; int co = rem % 144; int layer = rem / 144;
  const float* src = wr + (size_t)((layer * 144 + co) * 144 + ci) * 25;
  char* dstL = wph + (size_t)layer * WPH8;
  int m = co >> 4, l_lo = co & 15;
#pragma unroll
  for (int tap = 0; tap < 13; ++tap) {
    int ky = (tap >= 5) + (tap >= 10);
    int kx = tap - ky * 5;
    int k = ((ci >> 3) * 13 + tap) * 8 + (ci & 7);
    int chunk = k >> 7, kr = k & 127, g = kr >> 5, e = kr & 31;
    dstL[(size_t)(chunk * 9 + m) * 2048 + (e >> 4) * 1024 + (g * 16 + l_lo) * 16 + (e & 15)]
        = (char)f2e4(src[ky * 5 + kx]);
  }
}
__global__ void k_pack_f8(const float* __restrict__ wf, char* __restrict__ wpf) {
  int idx = blockIdx.x * 256 + threadIdx.x;
  if (idx >= 49 * 144) return;
  int ci = idx % 144; int co = idx / 144;
  const float* src = wf + (size_t)(co * 144 + ci) * 25;
  int m = co >> 4, l_lo = co & 15;
#pragma unroll
  for (int tap = 0; tap < 13; ++tap) {
    int ky = (tap >= 5) + (tap >= 10);
    int kx = tap - ky * 5;
    int k = ((ci >> 3) * 13 + tap) * 8 + (ci & 7);
    int chunk = k >> 7, kr = k & 127, g = kr >> 5, e = kr & 31;
    wpf[(size_t)(chunk * 4 + m) * 2048 + (e >> 4) * 1024 + (g * 16 + l_lo) * 16 + (e & 15)]
        = (char)f2e4(src[ky * 5 + kx]);
  }
}
__global__ void k_biaspad(const float* __restrict__ bf, float* __restrict__ bfp) {
  int i = threadIdx.x;
  bfp[i] = (i < 49) ? bf[i] : -1e30f;
}

// zero fp8 activation pads: rows 0-1 full (544 slots) + rows 2..257 slots
// {14,15,528,529} (px -2,-1,512,513), both buffers, all 18 planes.
__global__ void k_zeropad8(char* __restrict__ a8, char* __restrict__ b8) {
  int i = blockIdx.x * 256 + threadIdx.x;
  if (i >= 2 * 18 * 2112) return;
  int s = i % 2112; int p = i / 2112; int cig = p % 18; int buf = p / 18;
  char* base = (buf ? b8 : a8) + (size_t)cig * CGF8;
  int row, slot;
  if (s < 1088) { row = s / 544; slot = s - row * 544; }
  else { int s2 = s - 1088; row = 2 + (s2 >> 2); int m = s2 & 3; slot = (m < 2) ? (14 + m) : (526 + m); }
  uint2 z; z.x = 0u; z.y = 0u;
  *(uint2*)(base + (size_t)row * ROWF8 + (size_t)slot * 8) = z;
}

// ---------------- first layer: 1 -> 144, strictly causal (12 taps) ----------------
__global__ void k_layer0(const float* __restrict__ x, const float* __restrict__ w0,
                         const float* __restrict__ b0, char* __restrict__ act8) {
  int i = blockIdx.x * 256 + threadIdx.x;   // one thread per pixel
  int y = i >> 9, xx = i & 511;
  float xv[12];
#pragma unroll
  for (int tp = 0; tp < 12; ++tp) {
    int ky = (tp >= 5) + (tp >= 10);
    int kx = tp - ky * 5;
    int yy = y + ky - 2, xs = xx + kx - 2;
    bool ok = (yy >= 0) && (xs >= 0) && (xs < W);
    xv[tp] = ok ? x[yy * W + xs] : 0.f;
  }
  char* ob8 = act8 + (size_t)(y + 2) * ROWF8 + (size_t)(xx + 16) * 8;
  for (int cg = 0; cg < NCG; ++cg) {
    float av[8];
#pragma unroll
    for (int p = 0; p < 8; ++p) {
      int co = cg * 8 + p;
      float a = b0[co];
#pragma unroll
      for (int tp = 0; tp < 12; ++tp) {
        int ky = (tp >= 5) + (tp >= 10);
        int kx = tp - ky * 5;
        a += w0[co * 25 + ky * 5 + kx] * xv[tp];
      }
      av[p] = fmaxf(a, 0.f);
    }
    uint2 v8;
    v8.x = pk4e4(av[0], av[1], av[2], av[3]);
    v8.y = pk4e4(av[4], av[5], av[6], av[7]);
    *(uint2*)(ob8 + (size_t)cg * CGF8) = v8;
  }
}

// ---------------- hidden conv: 144 -> 144, 13 taps, MX-fp8 MFMA K=128 ----------------
// Residual lives in fp8 (in-place RMW on out8; input halo from the other
// buffer -> no race). Epilogue: shfl_xor(16)-merged full-line 128B stores,
// now 128B-ALIGNED via the 16-px halo (single full line per 16-lane group).
__global__ __launch_bounds__(256, 3)
void k_conv(const char* __restrict__ in, char* __restrict__ out8,
            const char* __restrict__ wp, const float* __restrict__ bias, int res) {
  __shared__ __align__(16) char lA[2][CHB8];
  const int tid = threadIdx.x;
  const int wid = tid >> 6, lane = tid & 63;
  const int col = lane & 15, g = lane >> 4;

  int bid = blockIdx.x;                 // 1024 blocks
  int xcd = bid & 7, idx = bid >> 3;    // idx in [0,128)
  int by = xcd * 8 + (idx >> 4), bx = idx & 15;   // XCD: contiguous 32-row band
  int y = by * 4 + wid, x0 = bx * 32;

  int pxo[2];                           // +14: halo 16 minus kx-center 2
#pragma unroll
  for (int t = 0; t < 2; ++t) pxo[t] = (x0 + 16 * t + col + 14) * XB8;
  const char* bbase = in + (size_t)y * ROWF8;

  f32x4 acc[9][2];
#pragma unroll
  for (int m = 0; m < 9; ++m)
#pragma unroll
    for (int t = 0; t < 2; ++t) acc[m][t] = (f32x4){0.f, 0.f, 0.f, 0.f};

  i32x8 bA[2], bB[2];

  // per-lane K state: base kgroup of this lane's k-block = 16c + 4g,
  // tracked as (cig, tap); advances +16 kgroups per chunk.
  int tap = 4 * g, cig = 0;
  auto bload = [&](i32x8 (&dst)[2]) __attribute__((always_inline)) {
#pragma unroll
    for (int s = 0; s < 4; ++s) {
      int ts = tap + s, cs = cig;
      if (ts >= 13) { ts -= 13; cs += 1; }
      if (cs >= 18) { cs = 0; ts = 0; }   // pad kgroups: zero weights, any valid addr
      int ky = (ts >= 5) + (ts >= 10);
      int kx = ts - ky * 5;
      int off = cs * (int)CGF8 + ky * (int)ROWF8 + kx * 8;
#pragma unroll
      for (int t = 0; t < 2; ++t) {
        uint2 u = *(const uint2*)(bbase + (size_t)(off + pxo[t]));
        dst[t][2 * s] = (int)u.x; dst[t][2 * s + 1] = (int)u.y;
      }
    }
    tap += 3; ++cig; if (tap >= 13) { tap -= 13; ++cig; }
  };

  // 18 DMA instr per chunk split over 4 waves (5,5,4,4)
  auto stage = [&](char* ldsn, int c) __attribute__((always_inline)) {
    const char* wsrc = wp + (size_t)c * CHB8;
#pragma unroll
    for (int j0 = 0; j0 < 5; ++j0) {
      int j = wid + j0 * 4;
      if (j < 18) gload_lds16(wsrc + (size_t)j * 1024 + (lane << 4), ldsn + j * 1024);
    }
  };

  auto domfma = [&](const char* ldsc, i32x8 (&b)[2]) __attribute__((always_inline)) {
    __builtin_amdgcn_s_setprio(1);
#pragma unroll
    for (int m = 0; m < 9; ++m) {
      i32x4 lo = *(const i32x4*)(ldsc + m * 2048 + (lane << 4));
      i32x4 hi = *(const i32x4*)(ldsc + m * 2048 + 1024 + (lane << 4));
      i32x8 a = __builtin_shufflevector(lo, hi, 0, 1, 2, 3, 4, 5, 6, 7);
#pragma unroll
      for (int t = 0; t < 2; ++t) acc[m][t] = mfma8(a, b[t], acc[m][t]);
    }
    __builtin_amdgcn_s_setprio(0);
  };

  auto phase = [&](const char* ldsc, char* ldsn, i32x8 (&bcur)[2], i32x8 (&bnext)[2],
                   int c) __attribute__((always_inline)) {
    stage(ldsn, c + 1);
    asm volatile("" ::: "memory");      // stage issues precede B prefetch (vmcnt order)
    bload(bnext);                       // chunk c+1
    asm volatile("" ::: "memory");
    domfma(ldsc, bcur);
    asm volatile("s_waitcnt vmcnt(8)" ::: "memory");  // stage done; 8 B loads in flight
    __builtin_amdgcn_s_barrier();
    asm volatile("" ::: "memory");
  };

  // prologue: chunk 0
  stage(&lA[0][0], 0);
  asm volatile("" ::: "memory");
  bload(bA);                            // chunk 0
  asm volatile("s_waitcnt vmcnt(8)" ::: "memory");
  __builtin_amdgcn_s_barrier();
  asm volatile("" ::: "memory");

#pragma unroll 1
  for (int c = 0; c < NCH8 - 1; c += 2) {   // 7 pairs: chunks 0..13
    phase(&lA[0][0], &lA[1][0], bA, bB, c);
    phase(&lA[1][0], &lA[0][0], bB, bA, c + 1);
  }
  domfma(&lA[0][0], bA);                // chunk 14 (even -> buffer 0)

  // epilogue: +bias, relu, fp8 residual (in place), shfl-merged 128B-line stores.
  // C/D: col=lane&15(px), row=(lane>>4)*4+r -> co = m*16 + g*4 + r.
#pragma unroll
  for (int m = 0; m < 9; ++m) {
    int co0 = m * 16 + (g << 2);
    f32x4 bv = *(const f32x4*)(bias + co0);
    int plane = m * 2 + (g >> 1);
#pragma unroll
    for (int t = 0; t < 2; ++t) {
      int px = x0 + 16 * t + col;
      float v0 = fmaxf(acc[m][t][0] + bv[0], 0.f);
      float v1 = fmaxf(acc[m][t][1] + bv[1], 0.f);
      float v2 = fmaxf(acc[m][t][2] + bv[2], 0.f);
      float v3 = fmaxf(acc[m][t][3] + bv[3], 0.f);
      float w0 = __shfl_xor(v0, 16);    // partner quarter-wave (g^1)
      float w1 = __shfl_xor(v1, 16);
      float w2 = __shfl_xor(v2, 16);
      float w3 = __shfl_xor(v3, 16);
      if ((g & 1) == 0) {
        char* o8 = out8 + (size_t)plane * CGF8 + (size_t)(y + 2) * ROWF8
                 + (size_t)(px + 16) * 8;
        if (res) {
          uint2 hv = *(const uint2*)o8;
          v0 += __builtin_amdgcn_cvt_f32_fp8((int)hv.x, 0);
          v1 += __builtin_amdgcn_cvt_f32_fp8((int)hv.x, 1);
          v2 += __builtin_amdgcn_cvt_f32_fp8((int)hv.x, 2);
          v3 += __builtin_amdgcn_cvt_f32_fp8((int)hv.x, 3);
          w0 += __builtin_amdgcn_cvt_f32_fp8((int)hv.y, 0);
          w1 += __builtin_amdgcn_cvt_f32_fp8((int)hv.y, 1);
          w2 += __builtin_amdgcn_cvt_f32_fp8((int)hv.y, 2);
          w3 += __builtin_amdgcn_cvt_f32_fp8((int)hv.y, 3);
        }
        uint2 st;
        st.x = pk4e4(v0, v1, v2, v3);
        st.y = pk4e4(w0, w1, w2, w3);
        *(uint2*)o8 = st;
      }
    }
  }
}

// ---------------- final conv (144 -> 49 padded 64, fp8) + softmax ----------------
__global__ __launch_bounds__(256, 4)
void k_convf(const char* __restrict__ in, float* __restrict__ probs,
             const char* __restrict__ wp, const float* __restrict__ bfp) {
  __shared__ __align__(16) char lA[2][CHBF8];
  const int tid = threadIdx.x;
  const int wid = tid >> 6, lane = tid & 63;
  const int col = lane & 15, g = lane >> 4;

  int bid = blockIdx.x;
  int xcd = bid & 7, idx = bid >> 3;
  int by = xcd * 8 + (idx >> 4), bx = idx & 15;
  int y = by * 4 + wid, x0 = bx * 32;

  int pxo[2];
#pragma unroll
  for (int t = 0; t < 2; ++t) pxo[t] = (x0 + 16 * t + col + 14) * XB8;
  const char* bbase = in + (size_t)y * ROWF8;

  f32x4 acc[4][2];
#pragma unroll
  for (int m = 0; m < 4; ++m)
#pragma unroll
    for (int t = 0; t < 2; ++t) acc[m][t] = (f32x4){0.f, 0.f, 0.f, 0.f};

  i32x8 bA[2], bB[2];

  int tap = 4 * g, cig = 0;
  auto bload = [&](i32x8 (&dst)[2]) __attribute__((always_inline)) {
#pragma unroll
    for (int s = 0; s < 4; ++s) {
      int ts = tap + s, cs = cig;
      if (ts >= 13) { ts -= 13; cs += 1; }
      if (cs >= 18) { cs = 0; ts = 0; }
      int ky = (ts >= 5) + (ts >= 10);
      int kx = ts - ky * 5;
      int off = cs * (int)CGF8 + ky * (int)ROWF8 + kx * 8;
#pragma unroll
      for (int t = 0; t < 2; ++t) {
        uint2 u = *(const uint2*)(bbase + (size_t)(off + pxo[t]));
        dst[t][2 * s] = (int)u.x; dst[t][2 * s + 1] = (int)u.y;
      }
    }
    tap += 3; ++cig; if (tap >= 13) { tap -= 13; ++cig; }
  };

  auto stage = [&](char* ldsn, int c) __attribute__((always_inline)) {
    const char* wsrc = wp + (size_t)c * CHBF8;
#pragma unroll
    for (int j0 = 0; j0 < 2; ++j0) {
      int j = wid + j0 * 4;
      gload_lds16(wsrc + (size_t)j * 1024 + (lane << 4), ldsn + j * 1024);
    }
  };

  auto domfma = [&](const char* ldsc, i32x8 (&b)[2]) __attribute__((always_inline)) {
    __builtin_amdgcn_s_setprio(1);
#pragma unroll
    for (int m = 0; m < 4; ++m) {
      i32x4 lo = *(const i32x4*)(ldsc + m * 2048 + (lane << 4));
      i32x4 hi = *(const i32x4*)(ldsc + m * 2048 + 1024 + (lane << 4));
      i32x8 a = __builtin_shufflevector(lo, hi, 0, 1, 2, 3, 4, 5, 6, 7);
#pragma unroll
      for (int t = 0; t < 2; ++t) acc[m][t] = mfma8(a, b[t], acc[m][t]);
    }
    __builtin_amdgcn_s_setprio(0);
  };

  auto phase = [&](const char* ldsc, char* ldsn, i32x8 (&bcur)[2], i32x8 (&bnext)[2],
                   int c) __attribute__((always_inline)) {
    stage(ldsn, c + 1);
    asm volatile("" ::: "memory");
    bload(bnext);
    asm volatile("" ::: "memory");
    domfma(ldsc, bcur);
    asm volatile("s_waitcnt vmcnt(8)" ::: "memory");
    __builtin_amdgcn_s_barrier();
    asm volatile("" ::: "memory");
  };

  stage(&lA[0][0], 0);
  asm volatile("" ::: "memory");
  bload(bA);
  asm volatile("s_waitcnt vmcnt(8)" ::: "memory");
  __builtin_amdgcn_s_barrier();
  asm volatile("" ::: "memory");

#pragma unroll 1
  for (int c = 0; c < NCH8 - 1; c += 2) {
    phase(&lA[0][0], &lA[1][0], bA, bB, c);
    phase(&lA[1][0], &lA[0][0], bB, bA, c + 1);
  }
  domfma(&lA[0][0], bA);

  // softmax over 49 channels per pixel; lanes (col, g0..3) hold the channel spread
#pragma unroll
  for (int t = 0; t < 2; ++t) {
    float lg[4][4];
    float mx = -1e30f;
#pragma unroll
    for (int m = 0; m < 4; ++m) {
      f32x4 bv = *(const f32x4*)(bfp + m * 16 + (g << 2));
#pragma unroll
      for (int r = 0; r < 4; ++r) {
        lg[m][r] = acc[m][t][r] + bv[r];
        mx = fmaxf(mx, lg[m][r]);
      }
    }
    mx = fmaxf(mx, __shfl_xor(mx, 16));
    mx = fmaxf(mx, __shfl_xor(mx, 32));
    float s = 0.f;
#pragma unroll
    for (int m = 0; m < 4; ++m)
#pragma unroll
      for (int r = 0; r < 4; ++r) {
        lg[m][r] = __expf(lg[m][r] - mx);
        s += lg[m][r];
      }
    s += __shfl_xor(s, 16);
    s += __shfl_xor(s, 32);
    float inv = 1.f / s;
    int xp = x0 + 16 * t + col;
    float* op = probs + (size_t)y * W + xp;
#pragma unroll
    for (int m = 0; m < 4; ++m)
#pragma unroll
      for (int r = 0; r < 4; ++r) {
        int co = m * 16 + (g << 2) + r;
        if (co < 49) op[(size_t)co * (H * W)] = lg[m][r] * inv;
      }
  }
}

// ---------------- importance mask + depth-to-space ----------------
__global__ void k_tmask(const float* __restrict__ x, float* __restrict__ out1) {
  int i = blockIdx.x * 256 + threadIdx.x;   // over 512*1024 outputs per g
  int yy = i >> 10, xx = i & 1023;
  float xv = x[(yy >> 1) * W + (xx >> 1)];
  float tc = floorf((xv + 1.0f) / (float)(2.0 / 47.0) + 1e-5f);
#pragma unroll 4
  for (int g = 0; g < 48; ++g)
    out1[(size_t)g * (512 * 1024) + i] = ((float)g < tc) ? 1.0f : 0.0f;
}

extern "C" void kernel_launch(void* const* d_in, const int* in_sizes, int n_in,
                              void* d_out, int out_size, void* d_ws, size_t ws_size,
                              hipStream_t stream) {
  const float* x  = (const float*)d_in[0];
  const float* w0 = (const float*)d_in[1];
  const float* b0 = (const float*)d_in[2];
  const float* wr = (const float*)d_in[3];
  const float* br = (const float*)d_in[4];
  const float* wf = (const float*)d_in[5];
  const float* bf = (const float*)d_in[6];

  char* ws    = (char*)d_ws;
  char* a8    = ws;                     // fp8 h stream (residual lives here)
  char* b8    = ws + ACTF8;             // fp8 y stream
  char* wph8  = ws + 2 * ACTF8;
  char* wpf8  = wph8 + 10 * WPH8;
  float* bfp  = (float*)(wpf8 + WPF8);

  // zero fp8 weight pad regions (kgroups 234-239, final co 49..63) + bfp tail
  hipMemsetAsync(wph8, 0, 10 * WPH8 + WPF8 + 256, stream);
  // zero fp8 activation pads
  k_zeropad8<<<(2 * 18 * 2112 + 255) / 256, 256, 0, stream>>>(a8, b8);

  k_pack_h8<<<(10 * 144 * 144 + 255) / 256, 256, 0, stream>>>(wr, wph8);
  k_pack_f8<<<(49 * 144 + 255) / 256, 256, 0, stream>>>(wf, wpf8);
  k_biaspad<<<1, 64, 0, stream>>>(bf, bfp);

  k_layer0<<<512, 256, 0, stream>>>(x, w0, b0, a8);

  for (int i = 0; i < 5; ++i) {
    // y = relu(conv(h)): a8 -> b8
    k_conv<<<1024, 256, 0, stream>>>(a8, b8, wph8 + (size_t)(2 * i) * WPH8,
                                     br + (2 * i) * 144, 0);
    // h = h + relu(conv(y)): b8 -> a8 (residual read-modify-write in place)
    k_conv<<<1024, 256, 0, stream>>>(b8, a8, wph8 + (size_t)(2 * i + 1) * WPH8,
                                     br + (2 * i + 1) * 144, 1);
  }

  float* probs = (float*)d_out;
  k_convf<<<1024, 256, 0, stream>>>(a8, probs, wpf8, bfp);
  k_tmask<<<2048, 256, 0, stream>>>(x, probs + (size_t)49 * H * W);
}